// Round 1
// baseline (437.618 us; speedup 1.0000x reference)
//
#include <hip/hip_runtime.h>

#define B_ 2
#define S_ 2048
#define D_ 1024
#define H_ 16
#define DK_ 64

typedef __attribute__((ext_vector_type(8))) short vshort8;   // 8 x bf16 (4 VGPRs)
typedef __attribute__((ext_vector_type(4))) float vfloat4;   // MFMA C/D

// f32 -> bf16 round-to-nearest-even (no NaNs in this problem)
static __device__ inline unsigned short f2bf(float f) {
    unsigned int x = __float_as_uint(f);
    x += 0x7fffu + ((x >> 16) & 1u);
    return (unsigned short)(x >> 16);
}

// ---------------------------------------------------------------------------
// Cast up to 4 f32 tensors to bf16. blockIdx.z selects tensor; each thread
// converts 8 elements (two float4 loads -> one uint4 store).
// ---------------------------------------------------------------------------
__global__ __launch_bounds__(256) void cast_bf16_kernel(
    const float* s0, const float* s1, const float* s2, const float* s3,
    unsigned short* d0, unsigned short* d1, unsigned short* d2, unsigned short* d3)
{
    int z = blockIdx.z;
    const float* s = (z == 0) ? s0 : (z == 1) ? s1 : (z == 2) ? s2 : s3;
    unsigned short* d = (z == 0) ? d0 : (z == 1) ? d1 : (z == 2) ? d2 : d3;
    int i = (blockIdx.x * 256 + threadIdx.x) * 8;
    float4 f0 = *(const float4*)(s + i);
    float4 f1 = *(const float4*)(s + i + 4);
    uint4 o;
    o.x = (unsigned int)f2bf(f0.x) | ((unsigned int)f2bf(f0.y) << 16);
    o.y = (unsigned int)f2bf(f0.z) | ((unsigned int)f2bf(f0.w) << 16);
    o.z = (unsigned int)f2bf(f1.x) | ((unsigned int)f2bf(f1.y) << 16);
    o.w = (unsigned int)f2bf(f1.z) | ((unsigned int)f2bf(f1.w) << 16);
    *(uint4*)(d + i) = o;
}

// ---------------------------------------------------------------------------
// GEMM: out[M][N] = A[M][K] @ W[N][K]^T + bias, bf16 inputs, f32 out.
// 128x128 block tile, BK=32, 256 threads (4 waves), 64x64 per wave.
// MFMA 16x16x32 bf16: A/B frag [idx=lane&15][k=quad*8+j], C/D row=quad*4+r, col=lane&15.
// LDS row stride padded to 40 elems (80 B) to break bank-conflict strides.
// ---------------------------------------------------------------------------
__global__ __launch_bounds__(256) void gemm_bt_kernel(
    const unsigned short* __restrict__ A,
    const unsigned short* __restrict__ Wt,
    const float* __restrict__ bias,
    float* __restrict__ out,
    int M, int N, int K)
{
    __shared__ unsigned short As[128][40];
    __shared__ unsigned short Ws[128][40];

    const int tid  = threadIdx.x;
    const int wave = tid >> 6;
    const int lane = tid & 63;
    const int l15  = lane & 15;
    const int quad = lane >> 4;
    const int wm   = wave >> 1;          // 0..1
    const int wn   = wave & 1;           // 0..1
    const int m0   = blockIdx.y * 128;
    const int n0   = blockIdx.x * 128;

    vfloat4 acc[4][4];
    for (int rt = 0; rt < 4; rt++)
        for (int ct = 0; ct < 4; ct++) {
            vfloat4 z = {0.f, 0.f, 0.f, 0.f};
            acc[rt][ct] = z;
        }

    const int srow = tid >> 2;           // 0..63
    const int scol = (tid & 3) * 8;      // 0,8,16,24

    for (int k0 = 0; k0 < K; k0 += 32) {
        *(uint4*)&As[srow][scol]      = *(const uint4*)&A [(long)(m0 + srow)      * K + k0 + scol];
        *(uint4*)&As[srow + 64][scol] = *(const uint4*)&A [(long)(m0 + srow + 64) * K + k0 + scol];
        *(uint4*)&Ws[srow][scol]      = *(const uint4*)&Wt[(long)(n0 + srow)      * K + k0 + scol];
        *(uint4*)&Ws[srow + 64][scol] = *(const uint4*)&Wt[(long)(n0 + srow + 64) * K + k0 + scol];
        __syncthreads();

        vshort8 af[4], bf[4];
        for (int rt = 0; rt < 4; rt++)
            af[rt] = *(const vshort8*)&As[wm * 64 + rt * 16 + l15][quad * 8];
        for (int ct = 0; ct < 4; ct++)
            bf[ct] = *(const vshort8*)&Ws[wn * 64 + ct * 16 + l15][quad * 8];
        for (int rt = 0; rt < 4; rt++)
            for (int ct = 0; ct < 4; ct++)
                acc[rt][ct] = __builtin_amdgcn_mfma_f32_16x16x32_bf16(af[rt], bf[ct], acc[rt][ct], 0, 0, 0);
        __syncthreads();
    }

    for (int rt = 0; rt < 4; rt++) {
        int row = m0 + wm * 64 + rt * 16 + quad * 4;
        for (int ct = 0; ct < 4; ct++) {
            int col = n0 + wn * 64 + ct * 16 + l15;
            float bv = bias[col];
            for (int r = 0; r < 4; r++)
                out[(long)(row + r) * N + col] = acc[rt][ct][r] + bv;
        }
    }
}

// ---------------------------------------------------------------------------
// RMSNorm + RoPE + bf16 cast + (B,S,D)->(B,H,S,DK) relayout.
// One wave per (b,s,h) row of 64. mode: 0=Q (norm+rope, *0.125), 1=K (norm+rope),
// 2=V (cast only).
// ---------------------------------------------------------------------------
__global__ __launch_bounds__(256) void normrope_kernel(
    const float* __restrict__ x,      // (B*S, D) f32
    const float* __restrict__ cosb,   // (S, DK)
    const float* __restrict__ sinb,   // (S, DK)
    const float* __restrict__ w,      // (DK)
    unsigned short* __restrict__ out, // (B,H,S,DK) bf16
    int mode)
{
    int wave = threadIdx.x >> 6;
    int lane = threadIdx.x & 63;
    int g = blockIdx.x * 4 + wave;    // 0 .. B*S*H-1
    int i = g >> 4;                   // b*S + s
    int h = g & 15;
    int s = i & (S_ - 1);
    int b = i >> 11;

    float v = x[(long)i * D_ + h * DK_ + lane];
    float val;
    if (mode == 2) {
        val = v;
    } else {
        float ss = v * v;
        for (int off = 1; off < 64; off <<= 1) ss += __shfl_xor(ss, off, 64);
        float rn = rsqrtf(ss * (1.0f / 64.0f) + 1e-6f);
        float xn = v * rn * w[lane];
        float other = __shfl_xor(xn, 32, 64);
        float rot = (lane < 32) ? -other : other;
        val = xn * cosb[s * DK_ + lane] + rot * sinb[s * DK_ + lane];
        if (mode == 0) val *= 0.125f;   // fold 1/sqrt(DK) into Q (exact)
    }
    out[((long)(b * H_ + h) * S_ + s) * DK_ + lane] = f2bf(val);
}

// ---------------------------------------------------------------------------
// Causal flash attention. Grid (S/64 q-tiles, B*H). Block = 256 = 4 waves;
// wave w owns q rows [q0+16w, q0+16w+16). K/V tiles of 64 kv positions.
// Q pre-scaled by 1/8. V staged transposed in LDS so PV B-frags are b128 reads.
// P goes through LDS (C-layout -> A-layout round trip).
// ---------------------------------------------------------------------------
__global__ __launch_bounds__(256) void attn_kernel(
    const unsigned short* __restrict__ Q,   // (B*H, S, DK) bf16
    const unsigned short* __restrict__ Kt,  // (B*H, S, DK) bf16
    const unsigned short* __restrict__ V,   // (B*H, S, DK) bf16
    unsigned short* __restrict__ O)         // (B, S, D) bf16
{
    __shared__ unsigned short Qs [64][72];
    __shared__ unsigned short Ks [64][72];
    __shared__ unsigned short Vts[64][72];  // V^T: [dk][kv]
    __shared__ unsigned short Ps [64][72];

    const int tid  = threadIdx.x;
    const int wave = tid >> 6;
    const int lane = tid & 63;
    const int l15  = lane & 15;
    const int quad = lane >> 4;
    const int qt   = blockIdx.x;
    const int bh   = blockIdx.y;
    const int b    = bh >> 4;
    const int h    = bh & 15;
    const int q0   = qt * 64;
    const long base = (long)bh * S_ * DK_;

    {   // stage Q tile (64 x 64)
        int r = tid >> 3;
        int c = (tid & 7) * 8;
        *(uint4*)&Qs[r][c]      = *(const uint4*)&Q[base + (long)(q0 + r)      * DK_ + c];
        *(uint4*)&Qs[r + 32][c] = *(const uint4*)&Q[base + (long)(q0 + r + 32) * DK_ + c];
    }
    __syncthreads();
    vshort8 aq0 = *(const vshort8*)&Qs[wave * 16 + l15][quad * 8];
    vshort8 aq1 = *(const vshort8*)&Qs[wave * 16 + l15][32 + quad * 8];

    vfloat4 Oacc[4];
    for (int dt = 0; dt < 4; dt++) { vfloat4 z = {0.f,0.f,0.f,0.f}; Oacc[dt] = z; }
    float m_run[4], l_run[4];
    for (int r = 0; r < 4; r++) { m_run[r] = -1e30f; l_run[r] = 0.f; }

    const int nkt = qt + 1;
    for (int kt = 0; kt < nkt; kt++) {
        const int k0 = kt * 64;
        {   // stage K tile + V^T tile
            int r = tid >> 3;
            int c = (tid & 7) * 8;
            *(uint4*)&Ks[r][c]      = *(const uint4*)&Kt[base + (long)(k0 + r)      * DK_ + c];
            *(uint4*)&Ks[r + 32][c] = *(const uint4*)&Kt[base + (long)(k0 + r + 32) * DK_ + c];
            uint4 v0 = *(const uint4*)&V[base + (long)(k0 + r)      * DK_ + c];
            uint4 v1 = *(const uint4*)&V[base + (long)(k0 + r + 32) * DK_ + c];
            const unsigned short* e0 = (const unsigned short*)&v0;
            const unsigned short* e1 = (const unsigned short*)&v1;
            for (int j = 0; j < 8; j++) {
                Vts[c + j][r]      = e0[j];
                Vts[c + j][r + 32] = e1[j];
            }
        }
        __syncthreads();

        // S = Q K^T  (16 x 64 per wave)
        vfloat4 sc[4];
        for (int ct = 0; ct < 4; ct++) {
            vfloat4 a = {0.f, 0.f, 0.f, 0.f};
            vshort8 b0 = *(const vshort8*)&Ks[ct * 16 + l15][quad * 8];
            vshort8 b1 = *(const vshort8*)&Ks[ct * 16 + l15][32 + quad * 8];
            a = __builtin_amdgcn_mfma_f32_16x16x32_bf16(aq0, b0, a, 0, 0, 0);
            a = __builtin_amdgcn_mfma_f32_16x16x32_bf16(aq1, b1, a, 0, 0, 0);
            sc[ct] = a;
        }

        if (kt == qt) {   // causal mask on diagonal tile (q0 == k0)
            for (int ct = 0; ct < 4; ct++) {
                int col = ct * 16 + l15;
                for (int r = 0; r < 4; r++) {
                    int rowi = wave * 16 + quad * 4 + r;
                    if (col > rowi) sc[ct][r] = -1e30f;
                }
            }
        }

        // online softmax (rows live in C-layout: row=quad*4+r, replicated over 16 lanes)
        float mnew[4], alpha[4];
        for (int r = 0; r < 4; r++) {
            float mx = fmaxf(fmaxf(sc[0][r], sc[1][r]), fmaxf(sc[2][r], sc[3][r]));
            for (int off = 1; off < 16; off <<= 1) mx = fmaxf(mx, __shfl_xor(mx, off, 64));
            mnew[r]  = fmaxf(m_run[r], mx);
            alpha[r] = __expf(m_run[r] - mnew[r]);
            m_run[r] = mnew[r];
        }
        float rs[4] = {0.f, 0.f, 0.f, 0.f};
        for (int ct = 0; ct < 4; ct++) {
            for (int r = 0; r < 4; r++) {
                float p = __expf(sc[ct][r] - mnew[r]);
                rs[r] += p;
                Ps[wave * 16 + quad * 4 + r][ct * 16 + l15] = f2bf(p);
            }
        }
        for (int r = 0; r < 4; r++) {
            for (int off = 1; off < 16; off <<= 1) rs[r] += __shfl_xor(rs[r], off, 64);
            l_run[r] = l_run[r] * alpha[r] + rs[r];
        }
        for (int dt = 0; dt < 4; dt++)
            for (int r = 0; r < 4; r++) Oacc[dt][r] *= alpha[r];
        __syncthreads();   // Ps visible

        // O += P V   (P: A-operand from Ps; V^T: B-operand, contiguous b128)
        vshort8 pa0 = *(const vshort8*)&Ps[wave * 16 + l15][quad * 8];
        vshort8 pa1 = *(const vshort8*)&Ps[wave * 16 + l15][32 + quad * 8];
        for (int dt = 0; dt < 4; dt++) {
            vshort8 b0 = *(const vshort8*)&Vts[dt * 16 + l15][quad * 8];
            vshort8 b1 = *(const vshort8*)&Vts[dt * 16 + l15][32 + quad * 8];
            Oacc[dt] = __builtin_amdgcn_mfma_f32_16x16x32_bf16(pa0, b0, Oacc[dt], 0, 0, 0);
            Oacc[dt] = __builtin_amdgcn_mfma_f32_16x16x32_bf16(pa1, b1, Oacc[dt], 0, 0, 0);
        }
        __syncthreads();   // done with Ks/Vts before restage
    }

    for (int r = 0; r < 4; r++) {
        float inv = 1.0f / l_run[r];
        int srow = q0 + wave * 16 + quad * 4 + r;
        for (int dt = 0; dt < 4; dt++) {
            int col = h * 64 + dt * 16 + l15;
            O[(long)(b * S_ + srow) * D_ + col] = f2bf(Oacc[dt][r] * inv);
        }
    }
}

// ---------------------------------------------------------------------------
extern "C" void kernel_launch(void* const* d_in, const int* in_sizes, int n_in,
                              void* d_out, int out_size, void* d_ws, size_t ws_size,
                              hipStream_t stream) {
    const float* q    = (const float*)d_in[0];
    const float* k    = (const float*)d_in[1];
    const float* v    = (const float*)d_in[2];
    // d_in[3] = mask (causal, known structure) -- unused
    const float* cosb = (const float*)d_in[4];
    const float* sinb = (const float*)d_in[5];
    const float* wq   = (const float*)d_in[6];
    const float* bq   = (const float*)d_in[7];
    const float* wk   = (const float*)d_in[8];
    const float* bk   = (const float*)d_in[9];
    const float* wv   = (const float*)d_in[10];
    const float* bv   = (const float*)d_in[11];
    const float* wo   = (const float*)d_in[12];
    const float* bo   = (const float*)d_in[13];
    const float* qn_w = (const float*)d_in[14];
    const float* kn_w = (const float*)d_in[15];

    const long MB = 1024 * 1024;
    char* ws = (char*)d_ws;
    unsigned short* xq  = (unsigned short*)(ws + 0 * MB);   // 8 MB each
    unsigned short* xk  = (unsigned short*)(ws + 8 * MB);
    unsigned short* xv  = (unsigned short*)(ws + 16 * MB);
    unsigned short* wqb = (unsigned short*)(ws + 24 * MB);  // 2 MB each
    unsigned short* wkb = (unsigned short*)(ws + 26 * MB);
    unsigned short* wvb = (unsigned short*)(ws + 28 * MB);
    unsigned short* wob = (unsigned short*)(ws + 30 * MB);
    float*          tmp = (float*)(ws + 32 * MB);           // 16 MB, reused
    unsigned short* Qn  = (unsigned short*)(ws + 48 * MB);  // 8 MB each
    unsigned short* Kn  = (unsigned short*)(ws + 56 * MB);
    unsigned short* Vb  = (unsigned short*)(ws + 64 * MB);
    unsigned short* Ob  = (unsigned short*)(ws + 72 * MB);

    dim3 blk(256);

    // casts: activations (3 x 4M elems), weights (4 x 1M elems)
    cast_bf16_kernel<<<dim3(2048, 1, 3), blk, 0, stream>>>(q, k, v, q, xq, xk, xv, xq);
    cast_bf16_kernel<<<dim3(512, 1, 4), blk, 0, stream>>>(wq, wk, wv, wo, wqb, wkb, wvb, wob);

    dim3 ggrid(8, 32);        // N/128, M/128
    dim3 ngrid(16384);        // B*S*H / 4 waves

    gemm_bt_kernel<<<ggrid, blk, 0, stream>>>(xq, wqb, bq, tmp, 4096, 1024, 1024);
    normrope_kernel<<<ngrid, blk, 0, stream>>>(tmp, cosb, sinb, qn_w, Qn, 0);
    gemm_bt_kernel<<<ggrid, blk, 0, stream>>>(xk, wkb, bk, tmp, 4096, 1024, 1024);
    normrope_kernel<<<ngrid, blk, 0, stream>>>(tmp, cosb, sinb, kn_w, Kn, 1);
    gemm_bt_kernel<<<ggrid, blk, 0, stream>>>(xv, wvb, bv, tmp, 4096, 1024, 1024);
    normrope_kernel<<<ngrid, blk, 0, stream>>>(tmp, cosb, sinb, qn_w, Vb, 2);

    attn_kernel<<<dim3(32, 32), blk, 0, stream>>>(Qn, Kn, Vb, Ob);

    gemm_bt_kernel<<<ggrid, blk, 0, stream>>>(Ob, wob, bo, (float*)d_out, 4096, 1024, 1024);
}